// Round 8
// baseline (373.182 us; speedup 1.0000x reference)
//
#include <hip/hip_runtime.h>
#include <hip/hip_bf16.h>

typedef __attribute__((ext_vector_type(8))) short bf16x8;
typedef __attribute__((ext_vector_type(4))) float f32x4;

#define K_DIM 64
#define LDSP  1026   // floats; breaks phase-1 write conflicts, phase-2 reads native

// ---------------- prep: one wave per row ----------------
__global__ __launch_bounds__(256) void rbf_prep(
    const float* __restrict__ src, int rows,
    __hip_bfloat16* __restrict__ hi, __hip_bfloat16* __restrict__ lo,
    float* __restrict__ norms,
    const float* __restrict__ log_sigmas, float* __restrict__ inv_sigma2)
{
    int row  = blockIdx.x * 4 + (threadIdx.x >> 6);
    int lane = threadIdx.x & 63;
    if (row >= rows) return;

    float v = src[(size_t)row * K_DIM + lane];
    __hip_bfloat16 h = __float2bfloat16(v);
    float hf = __bfloat162float(h);
    __hip_bfloat16 l = __float2bfloat16(v - hf);
    hi[(size_t)row * K_DIM + lane] = h;
    lo[(size_t)row * K_DIM + lane] = l;

    float s = v * v;
    #pragma unroll
    for (int off = 32; off > 0; off >>= 1) s += __shfl_down(s, off, 64);
    if (lane == 0) {
        norms[row] = s;
        if (inv_sigma2) inv_sigma2[row] = __expf(-2.0f * log_sigmas[row]);
    }
}

// ---------------- main: phase-split (compute-all, then stream-store) --------
// Block = 16 rows x 1024 cols (64 KB of output) staged entirely in LDS.
// PHASE 1 (loads only): 4 chunks of 256 cols, R4-verified MFMA orientation
//   (A=centres, B=x; D: col(lane&15)->M row, row(quad*4+reg)->4 consec N
//   cols), epilogue into LDS. Software-pipelined c-frag loads. NO STORES.
// barrier (cheap: no outstanding stores to drain).
// PHASE 2 (stores only): wave w streams rows 4w..4w+3 as 16 back-to-back
//   independent 1 KB dwordx4 stores, then s_endpgm (fire-and-forget drain).
// Per-wave vmem order = [loads][stores][end]: no load-wait ever follows a
// store, so stores are never dragged onto the critical path by in-order
// vmcnt accounting — the regime fillBufferAligned runs in (10.5 B/cyc/CU at
// 4 waves/CU). 65.7 KB LDS -> 2 blocks/CU: next block computes while this
// block's stores drain.
__global__ __launch_bounds__(256, 2) void rbf_main(
    const __hip_bfloat16* __restrict__ xhi, const __hip_bfloat16* __restrict__ xlo,
    const __hip_bfloat16* __restrict__ chi, const __hip_bfloat16* __restrict__ clo,
    const float* __restrict__ nx, const float* __restrict__ nc,
    const float* __restrict__ inv_sigma2,
    float* __restrict__ out, int N)
{
    __shared__ float buf[16][LDSP];

    const int wave = threadIdx.x >> 6;
    const int lane = threadIdx.x & 63;
    const int quad = lane >> 4;
    const int l16  = lane & 15;

    const int m_base = (blockIdx.x >> 2) << 4;    // 16 rows
    const int n_base = (blockIdx.x & 3) << 10;    // 1024 cols

    // x fragments: the block's 16 rows.
    const int bm = m_base + l16;
    const bf16x8 xh0 = *(const bf16x8*)(xhi + (size_t)bm * K_DIM +      quad * 8);
    const bf16x8 xh1 = *(const bf16x8*)(xhi + (size_t)bm * K_DIM + 32 + quad * 8);
    const bf16x8 xl0 = *(const bf16x8*)(xlo + (size_t)bm * K_DIM +      quad * 8);
    const bf16x8 xl1 = *(const bf16x8*)(xlo + (size_t)bm * K_DIM + 32 + quad * 8);
    const float  nxm = nx[bm];

    // Per-lane c-frag base: row (n_base + wave*64 + l16), k-chunk quad*8.
    const size_t crow = (size_t)(n_base + (wave << 6) + l16) * K_DIM + quad * 8;
    const __hip_bfloat16* chb = chi + crow;
    const __hip_bfloat16* clb = clo + crow;

    auto load_set = [&](int j, bf16x8 h0[4], bf16x8 h1[4], bf16x8 l0[4], bf16x8 l1[4]) {
        const int base = j * (256 * K_DIM);
        #pragma unroll
        for (int nt = 0; nt < 4; ++nt) {
            const int o = base + nt * (16 * K_DIM);
            h0[nt] = *(const bf16x8*)(chb + o);
            h1[nt] = *(const bf16x8*)(chb + o + 32);
            l0[nt] = *(const bf16x8*)(clb + o);
            l1[nt] = *(const bf16x8*)(clb + o + 32);
        }
    };

    auto compute = [&](int j, bf16x8 h0[4], bf16x8 h1[4], bf16x8 l0[4], bf16x8 l1[4]) {
        const int cw = (j << 8) + (wave << 6);        // wave's col offset in block
        #pragma unroll
        for (int nt = 0; nt < 4; ++nt) {
            f32x4 acc = {0.f, 0.f, 0.f, 0.f};
            acc = __builtin_amdgcn_mfma_f32_16x16x32_bf16(h0[nt], xh0, acc, 0, 0, 0);
            acc = __builtin_amdgcn_mfma_f32_16x16x32_bf16(h1[nt], xh1, acc, 0, 0, 0);
            acc = __builtin_amdgcn_mfma_f32_16x16x32_bf16(h0[nt], xl0, acc, 0, 0, 0);
            acc = __builtin_amdgcn_mfma_f32_16x16x32_bf16(h1[nt], xl1, acc, 0, 0, 0);
            acc = __builtin_amdgcn_mfma_f32_16x16x32_bf16(l0[nt], xh0, acc, 0, 0, 0);
            acc = __builtin_amdgcn_mfma_f32_16x16x32_bf16(l1[nt], xh1, acc, 0, 0, 0);

            const int col = cw + (nt << 4) + (quad << 2);      // in-block col
            const f32x4 nc4 = *(const f32x4*)(nc + n_base + col);
            const f32x4 iv4 = *(const f32x4*)(inv_sigma2 + n_base + col);
            f32x4 res;
            #pragma unroll
            for (int r = 0; r < 4; ++r) {
                float sq = fmaxf(nxm + nc4[r] - 2.0f * acc[r], 0.f);
                res[r] = __expf(-sq * iv4[r]);
            }
            *(f32x4*)&buf[l16][col] = res;
        }
    };

    bf16x8 Ah0[4], Ah1[4], Al0[4], Al1[4];
    bf16x8 Bh0[4], Bh1[4], Bl0[4], Bl1[4];

    // Phase 1: pipelined compute of 4 chunks (loads only in the vmem queue).
    load_set(0, Ah0, Ah1, Al0, Al1);
    load_set(1, Bh0, Bh1, Bl0, Bl1);
    compute(0, Ah0, Ah1, Al0, Al1);
    load_set(2, Ah0, Ah1, Al0, Al1);
    compute(1, Bh0, Bh1, Bl0, Bl1);
    load_set(3, Bh0, Bh1, Bl0, Bl1);
    compute(2, Ah0, Ah1, Al0, Al1);
    compute(3, Bh0, Bh1, Bl0, Bl1);

    __syncthreads();   // no outstanding stores -> cheap drain

    // Phase 2: pure store stream. Wave w: rows 4w..4w+3, 16 x 1 KB dwordx4.
    #pragma unroll
    for (int i = 0; i < 4; ++i) {
        const int row = (wave << 2) + i;
        float* orow = out + (size_t)(m_base + row) * N + n_base;
        #pragma unroll
        for (int s = 0; s < 4; ++s) {
            const int col = (s << 8) + (lane << 2);
            *(f32x4*)(orow + col) = *(const f32x4*)&buf[row][col];
        }
    }
}

// ---------------- fallback: fully fused (R2's passing kernel) ----------------
__device__ __forceinline__ void split8(const float* __restrict__ p,
                                       bf16x8& hi, bf16x8& lo, float& ss) {
    #pragma unroll
    for (int j = 0; j < 8; ++j) {
        float v = p[j];
        ss = fmaf(v, v, ss);
        __hip_bfloat16 h = __float2bfloat16(v);
        float hf = __bfloat162float(h);
        __hip_bfloat16 l = __float2bfloat16(v - hf);
        hi[j] = *reinterpret_cast<const short*>(&h);
        lo[j] = *reinterpret_cast<const short*>(&l);
    }
}

__global__ __launch_bounds__(256) void rbf_fused(
    const float* __restrict__ x, const float* __restrict__ c,
    const float* __restrict__ ls, float* __restrict__ out, int N)
{
    const int wave = threadIdx.x >> 6;
    const int lane = threadIdx.x & 63;
    const int quad = lane >> 4;
    const int l16  = lane & 15;

    const int m_base = (blockIdx.y << 6) + (wave << 4);
    const int n_base = blockIdx.x << 6;

    const int am = m_base + l16;
    const float* xp = x + (size_t)am * K_DIM;
    bf16x8 ahi0, alo0, ahi1, alo1;
    float ssx = 0.f;
    split8(xp + quad * 8,      ahi0, alo0, ssx);
    split8(xp + 32 + quad * 8, ahi1, alo1, ssx);
    ssx += __shfl_xor(ssx, 16, 64);
    ssx += __shfl_xor(ssx, 32, 64);
    float nxr[4];
    #pragma unroll
    for (int r = 0; r < 4; ++r) nxr[r] = __shfl(ssx, quad * 4 + r, 64);

    #pragma unroll
    for (int nt = 0; nt < 4; ++nt) {
        const int n = n_base + nt * 16 + l16;
        const float* cp = c + (size_t)n * K_DIM;
        bf16x8 bhi0, blo0, bhi1, blo1;
        float ssc = 0.f;
        split8(cp + quad * 8,      bhi0, blo0, ssc);
        split8(cp + 32 + quad * 8, bhi1, blo1, ssc);
        ssc += __shfl_xor(ssc, 16, 64);
        ssc += __shfl_xor(ssc, 32, 64);

        f32x4 acc = {0.f, 0.f, 0.f, 0.f};
        acc = __builtin_amdgcn_mfma_f32_16x16x32_bf16(ahi0, bhi0, acc, 0, 0, 0);
        acc = __builtin_amdgcn_mfma_f32_16x16x32_bf16(ahi1, bhi1, acc, 0, 0, 0);
        acc = __builtin_amdgcn_mfma_f32_16x16x32_bf16(ahi0, blo0, acc, 0, 0, 0);
        acc = __builtin_amdgcn_mfma_f32_16x16x32_bf16(ahi1, blo1, acc, 0, 0, 0);
        acc = __builtin_amdgcn_mfma_f32_16x16x32_bf16(alo0, bhi0, acc, 0, 0, 0);
        acc = __builtin_amdgcn_mfma_f32_16x16x32_bf16(alo1, bhi1, acc, 0, 0, 0);

        const float invv = __expf(-2.0f * ls[n]);
        #pragma unroll
        for (int r = 0; r < 4; ++r) {
            const int row = m_base + quad * 4 + r;
            float sq = fmaxf(nxr[r] + ssc - 2.0f * acc[r], 0.f);
            out[(size_t)row * N + n] = __expf(-sq * invv);
        }
    }
}

extern "C" void kernel_launch(void* const* d_in, const int* in_sizes, int n_in,
                              void* d_out, int out_size, void* d_ws, size_t ws_size,
                              hipStream_t stream) {
    const float* x  = (const float*)d_in[0];   // [M,64]
    const float* c  = (const float*)d_in[1];   // [N,64]
    const float* ls = (const float*)d_in[2];   // [N]
    float* out = (float*)d_out;                // [M,N]

    const int M = in_sizes[0] / K_DIM;   // 16384
    const int N = in_sizes[2];           // 4096

    size_t off = 0;
    auto place = [&](size_t bytes) { size_t p = off; off += (bytes + 255) & ~(size_t)255; return p; };
    size_t o_xhi = place((size_t)M * K_DIM * 2);
    size_t o_xlo = place((size_t)M * K_DIM * 2);
    size_t o_chi = place((size_t)N * K_DIM * 2);
    size_t o_clo = place((size_t)N * K_DIM * 2);
    size_t o_nx  = place((size_t)M * 4);
    size_t o_nc  = place((size_t)N * 4);
    size_t o_inv = place((size_t)N * 4);

    if (ws_size >= off) {
        char* ws = (char*)d_ws;
        __hip_bfloat16* xhi = (__hip_bfloat16*)(ws + o_xhi);
        __hip_bfloat16* xlo = (__hip_bfloat16*)(ws + o_xlo);
        __hip_bfloat16* chi = (__hip_bfloat16*)(ws + o_chi);
        __hip_bfloat16* clo = (__hip_bfloat16*)(ws + o_clo);
        float* nx  = (float*)(ws + o_nx);
        float* nc  = (float*)(ws + o_nc);
        float* inv = (float*)(ws + o_inv);

        rbf_prep<<<dim3((M + 3) / 4), 256, 0, stream>>>(x, M, xhi, xlo, nx, nullptr, nullptr);
        rbf_prep<<<dim3((N + 3) / 4), 256, 0, stream>>>(c, N, chi, clo, nc, ls, inv);
        rbf_main<<<dim3((M / 16) * (N / 1024)), 256, 0, stream>>>(xhi, xlo, chi, clo, nx, nc, inv, out, N);
    } else {
        rbf_fused<<<dim3(N / 64, M / 64), 256, 0, stream>>>(x, c, ls, out, N);
    }
}

// Round 10
// 370.007 us; speedup vs baseline: 1.0086x; 1.0086x over previous
//
#include <hip/hip_runtime.h>
#include <hip/hip_bf16.h>

typedef __attribute__((ext_vector_type(8))) short bf16x8;
typedef __attribute__((ext_vector_type(4))) float f32x4;

#define K_DIM  64
#define CPITCH 72          // shorts per c-row in the blob: 144 B rows -> 2-way (free) LDS frag reads
#define CHUNK_SHORTS 9728  // per 64-col chunk: hi 4608 + lo 4608 + nciv 512 shorts (19456 B)

// ---------------- prep_x: unpadded bf16 planes + row norms ----------------
__global__ __launch_bounds__(256) void rbf_prep_x(
    const float* __restrict__ src, int rows,
    __hip_bfloat16* __restrict__ hi, __hip_bfloat16* __restrict__ lo,
    float* __restrict__ norms)
{
    int row  = blockIdx.x * 4 + (threadIdx.x >> 6);
    int lane = threadIdx.x & 63;
    if (row >= rows) return;

    float v = src[(size_t)row * K_DIM + lane];
    __hip_bfloat16 h = __float2bfloat16(v);
    float hf = __bfloat162float(h);
    __hip_bfloat16 l = __float2bfloat16(v - hf);
    hi[(size_t)row * K_DIM + lane] = h;
    lo[(size_t)row * K_DIM + lane] = l;

    float s = v * v;
    #pragma unroll
    for (int off = 32; off > 0; off >>= 1) s += __shfl_down(s, off, 64);
    if (lane == 0) norms[row] = s;
}

// ---------------- prep_c: contiguous per-chunk blob -----------------------
// Chunk ck (64 c-rows) occupies blob[ck*9728 .. +9728) shorts:
//   [0,4608):    hi plane, row r at r*72, first 64 shorts valid
//   [4608,9216): lo plane, same layout
//   [9216,9728): as float[128]: [0..63]=||c||^2, [64..127]=exp(-2*ls), rest pad
__global__ __launch_bounds__(256) void rbf_prep_c(
    const float* __restrict__ src, int rows,
    short* __restrict__ blob, const float* __restrict__ log_sigmas)
{
    int row  = blockIdx.x * 4 + (threadIdx.x >> 6);
    int lane = threadIdx.x & 63;
    if (row >= rows) return;

    float v = src[(size_t)row * K_DIM + lane];
    __hip_bfloat16 h = __float2bfloat16(v);
    float hf = __bfloat162float(h);
    __hip_bfloat16 l = __float2bfloat16(v - hf);

    const int ck = row >> 6, r = row & 63;
    short* base = blob + (size_t)ck * CHUNK_SHORTS;
    base[r * CPITCH + lane]        = *(short*)&h;
    base[4608 + r * CPITCH + lane] = *(short*)&l;

    float s = v * v;
    #pragma unroll
    for (int off = 32; off > 0; off >>= 1) s += __shfl_down(s, off, 64);
    if (lane == 0) {
        float* f = (float*)(base + 9216);
        f[r]      = s;
        f[64 + r] = __expf(-2.0f * log_sigmas[row]);
    }
}

// ---------------- main: LDS-staged c via coalesced load+ds_write ----------
// Block = 32 rows x all N, swept in 64-col chunks. 512 thr = 8 waves:
// rg = wave&1 -> rows rg*16..+16; cq = wave>>1 -> chunk cols cq*16..+16.
// Staging: the 19456 B chunk blob is copied LDS-ward as 1216 f32x4 slots,
// thread t handling slots {t, t+512, t+1024<1216} — every global read is a
// full 128 B line shared by 8 lanes (R7's per-lane 128 B-strided frag loads
// touched 16 scattered half-lines per wave-load; that L1-thrash is the
// remaining theory for the 1.6-1.9 TB/s cap). Plain loads + ds_write_b128:
// vmcnt/lgkmcnt deps fully visible to the compiler (R9's global_load_lds DMA
// produced NaN — semantics too fragile to debug blind).
// Compute = R4-verified orientation (A=centres from LDS, B=x regs;
// D: col(lane&15)->M row, row(quad*4+reg)->N col). Double-buffered, one
// barrier per chunk; epilogue = 1 nontemporal f32x4 store per lane.
__global__ __launch_bounds__(512, 4) void rbf_main(
    const __hip_bfloat16* __restrict__ xhi, const __hip_bfloat16* __restrict__ xlo,
    const short* __restrict__ blob, const float* __restrict__ nx,
    float* __restrict__ out, int N)
{
    __shared__ __align__(16) short stage[2][CHUNK_SHORTS];

    const int tid  = threadIdx.x;
    const int wave = tid >> 6;
    const int lane = tid & 63;
    const int quad = lane >> 4;
    const int l16  = lane & 15;
    const int rg   = wave & 1;    // row group (16 rows)
    const int cq   = wave >> 1;   // col quarter of the 64-col chunk

    const int m_base = blockIdx.x << 5;   // 32 rows per block

    // x fragments (once per kernel)
    const int bm = m_base + (rg << 4) + l16;
    const bf16x8 xh0 = *(const bf16x8*)(xhi + (size_t)bm * K_DIM +      quad * 8);
    const bf16x8 xh1 = *(const bf16x8*)(xhi + (size_t)bm * K_DIM + 32 + quad * 8);
    const bf16x8 xl0 = *(const bf16x8*)(xlo + (size_t)bm * K_DIM +      quad * 8);
    const bf16x8 xl1 = *(const bf16x8*)(xlo + (size_t)bm * K_DIM + 32 + quad * 8);
    const float  nxm = nx[bm];
    float* const orow = out + (size_t)bm * N;

    const int NCHUNK = N >> 6;

    auto stage_chunk = [&](int ck, int sel) {
        const f32x4* src = (const f32x4*)(blob + (size_t)ck * CHUNK_SHORTS);
        f32x4* dst = (f32x4*)&stage[sel][0];
        f32x4 t0 = src[tid];
        f32x4 t1 = src[tid + 512];
        dst[tid]       = t0;
        dst[tid + 512] = t1;
        if (tid < 192) dst[tid + 1024] = src[tid + 1024];
    };

    stage_chunk(0, 0);

    for (int ck = 0; ck < NCHUNK; ++ck) {
        __syncthreads();   // stage(ck) visible; all waves past compute(ck-1)
        if (ck + 1 < NCHUNK) stage_chunk(ck + 1, (ck + 1) & 1);

        const int sel = ck & 1;
        const short* hbase = &stage[sel][0];
        const short* lbase = &stage[sel][4608];
        const float* fbase = (const float*)&stage[sel][9216];

        // this wave's 16x16 tile: chunk-local c-rows cq*16..+16
        const int off = ((cq << 4) + l16) * CPITCH + (quad << 3);
        const bf16x8 ch0 = *(const bf16x8*)(hbase + off);
        const bf16x8 ch1 = *(const bf16x8*)(hbase + off + 32);
        const bf16x8 cl0 = *(const bf16x8*)(lbase + off);
        const bf16x8 cl1 = *(const bf16x8*)(lbase + off + 32);

        f32x4 acc = {0.f, 0.f, 0.f, 0.f};
        acc = __builtin_amdgcn_mfma_f32_16x16x32_bf16(ch0, xh0, acc, 0, 0, 0);
        acc = __builtin_amdgcn_mfma_f32_16x16x32_bf16(ch1, xh1, acc, 0, 0, 0);
        acc = __builtin_amdgcn_mfma_f32_16x16x32_bf16(ch0, xl0, acc, 0, 0, 0);
        acc = __builtin_amdgcn_mfma_f32_16x16x32_bf16(ch1, xl1, acc, 0, 0, 0);
        acc = __builtin_amdgcn_mfma_f32_16x16x32_bf16(cl0, xh0, acc, 0, 0, 0);
        acc = __builtin_amdgcn_mfma_f32_16x16x32_bf16(cl1, xh1, acc, 0, 0, 0);

        const int jc = (cq << 4) + (quad << 2);   // chunk-local col of lane's 4 outputs
        const f32x4 nc4 = *(const f32x4*)&fbase[jc];
        const f32x4 iv4 = *(const f32x4*)&fbase[64 + jc];
        f32x4 res;
        #pragma unroll
        for (int r = 0; r < 4; ++r) {
            float sq = fmaxf(nxm + nc4[r] - 2.0f * acc[r], 0.f);
            res[r] = __expf(-sq * iv4[r]);
        }
        __builtin_nontemporal_store(res, (f32x4*)(orow + (ck << 6) + jc));
    }
}

// ---------------- fallback: fully fused (R2's passing kernel) ----------------
__device__ __forceinline__ void split8(const float* __restrict__ p,
                                       bf16x8& hi, bf16x8& lo, float& ss) {
    #pragma unroll
    for (int j = 0; j < 8; ++j) {
        float v = p[j];
        ss = fmaf(v, v, ss);
        __hip_bfloat16 h = __float2bfloat16(v);
        float hf = __bfloat162float(h);
        __hip_bfloat16 l = __float2bfloat16(v - hf);
        hi[j] = *reinterpret_cast<const short*>(&h);
        lo[j] = *reinterpret_cast<const short*>(&l);
    }
}

__global__ __launch_bounds__(256) void rbf_fused(
    const float* __restrict__ x, const float* __restrict__ c,
    const float* __restrict__ ls, float* __restrict__ out, int N)
{
    const int wave = threadIdx.x >> 6;
    const int lane = threadIdx.x & 63;
    const int quad = lane >> 4;
    const int l16  = lane & 15;

    const int m_base = (blockIdx.y << 6) + (wave << 4);
    const int n_base = blockIdx.x << 6;

    const int am = m_base + l16;
    const float* xp = x + (size_t)am * K_DIM;
    bf16x8 ahi0, alo0, ahi1, alo1;
    float ssx = 0.f;
    split8(xp + quad * 8,      ahi0, alo0, ssx);
    split8(xp + 32 + quad * 8, ahi1, alo1, ssx);
    ssx += __shfl_xor(ssx, 16, 64);
    ssx += __shfl_xor(ssx, 32, 64);
    float nxr[4];
    #pragma unroll
    for (int r = 0; r < 4; ++r) nxr[r] = __shfl(ssx, quad * 4 + r, 64);

    #pragma unroll
    for (int nt = 0; nt < 4; ++nt) {
        const int n = n_base + nt * 16 + l16;
        const float* cp = c + (size_t)n * K_DIM;
        bf16x8 bhi0, blo0, bhi1, blo1;
        float ssc = 0.f;
        split8(cp + quad * 8,      bhi0, blo0, ssc);
        split8(cp + 32 + quad * 8, bhi1, blo1, ssc);
        ssc += __shfl_xor(ssc, 16, 64);
        ssc += __shfl_xor(ssc, 32, 64);

        f32x4 acc = {0.f, 0.f, 0.f, 0.f};
        acc = __builtin_amdgcn_mfma_f32_16x16x32_bf16(ahi0, bhi0, acc, 0, 0, 0);
        acc = __builtin_amdgcn_mfma_f32_16x16x32_bf16(ahi1, bhi1, acc, 0, 0, 0);
        acc = __builtin_amdgcn_mfma_f32_16x16x32_bf16(ahi0, blo0, acc, 0, 0, 0);
        acc = __builtin_amdgcn_mfma_f32_16x16x32_bf16(ahi1, blo1, acc, 0, 0, 0);
        acc = __builtin_amdgcn_mfma_f32_16x16x32_bf16(alo0, bhi0, acc, 0, 0, 0);
        acc = __builtin_amdgcn_mfma_f32_16x16x32_bf16(alo1, bhi1, acc, 0, 0, 0);

        const float invv = __expf(-2.0f * ls[n]);
        #pragma unroll
        for (int r = 0; r < 4; ++r) {
            const int row = m_base + quad * 4 + r;
            float sq = fmaxf(nxr[r] + ssc - 2.0f * acc[r], 0.f);
            out[(size_t)row * N + n] = __expf(-sq * invv);
        }
    }
}

extern "C" void kernel_launch(void* const* d_in, const int* in_sizes, int n_in,
                              void* d_out, int out_size, void* d_ws, size_t ws_size,
                              hipStream_t stream) {
    const float* x  = (const float*)d_in[0];   // [M,64]
    const float* c  = (const float*)d_in[1];   // [N,64]
    const float* ls = (const float*)d_in[2];   // [N]
    float* out = (float*)d_out;                // [M,N]

    const int M = in_sizes[0] / K_DIM;   // 16384
    const int N = in_sizes[2];           // 4096

    size_t off = 0;
    auto place = [&](size_t bytes) { size_t p = off; off += (bytes + 255) & ~(size_t)255; return p; };
    size_t o_xhi  = place((size_t)M * K_DIM * 2);
    size_t o_xlo  = place((size_t)M * K_DIM * 2);
    size_t o_blob = place((size_t)(N / 64) * CHUNK_SHORTS * 2);
    size_t o_nx   = place((size_t)M * 4);

    if (ws_size >= off && (M % 32) == 0 && (N % 64) == 0) {
        char* ws = (char*)d_ws;
        __hip_bfloat16* xhi = (__hip_bfloat16*)(ws + o_xhi);
        __hip_bfloat16* xlo = (__hip_bfloat16*)(ws + o_xlo);
        short* blob = (short*)(ws + o_blob);
        float* nx   = (float*)(ws + o_nx);

        rbf_prep_x<<<dim3((M + 3) / 4), 256, 0, stream>>>(x, M, xhi, xlo, nx);
        rbf_prep_c<<<dim3((N + 3) / 4), 256, 0, stream>>>(c, N, blob, ls);
        rbf_main<<<dim3(M / 32), 512, 0, stream>>>(xhi, xlo, blob, nx, out, N);
    } else {
        rbf_fused<<<dim3(N / 64, M / 64), 256, 0, stream>>>(x, c, ls, out, N);
    }
}

// Round 11
// 305.569 us; speedup vs baseline: 1.2213x; 1.2109x over previous
//
#include <hip/hip_runtime.h>
#include <hip/hip_bf16.h>

typedef __attribute__((ext_vector_type(8))) short bf16x8;
typedef __attribute__((ext_vector_type(4))) float f32x4;

#define K_DIM 64
#define CPITCH 72          // shorts per c-row in band blob (144 B; R10-proven 2-way-free LDS frag reads)
#define BAND_SHORTS 20480  // per 128-col band: hi 9216 + lo 9216 + norms 1024 + pad (40960 B)

// ---------------- prep_x: bf16 hi/lo planes + row norms ----------------
__global__ __launch_bounds__(256) void rbf_prep_x(
    const float* __restrict__ src, int rows,
    __hip_bfloat16* __restrict__ hi, __hip_bfloat16* __restrict__ lo,
    float* __restrict__ norms)
{
    int row  = blockIdx.x * 4 + (threadIdx.x >> 6);
    int lane = threadIdx.x & 63;
    if (row >= rows) return;

    float v = src[(size_t)row * K_DIM + lane];
    __hip_bfloat16 h = __float2bfloat16(v);
    float hf = __bfloat162float(h);
    __hip_bfloat16 l = __float2bfloat16(v - hf);
    hi[(size_t)row * K_DIM + lane] = h;
    lo[(size_t)row * K_DIM + lane] = l;

    float s = v * v;
    #pragma unroll
    for (int off = 32; off > 0; off >>= 1) s += __shfl_down(s, off, 64);
    if (lane == 0) norms[row] = s;
}

// ---------------- prep_c: per-128-col-band blob -----------------------
// Band b (128 c-rows) at blob[b*20480 .. ) shorts:
//   [0,9216):      hi plane, row r at r*72 (first 64 shorts valid)
//   [9216,18432):  lo plane, same layout
//   [18432,19456): as float[256]: [0..127]=||c||^2, [128..255]=exp(-2*ls)
__global__ __launch_bounds__(256) void rbf_prep_c(
    const float* __restrict__ src, int rows,
    short* __restrict__ blob, const float* __restrict__ log_sigmas)
{
    int row  = blockIdx.x * 4 + (threadIdx.x >> 6);
    int lane = threadIdx.x & 63;
    if (row >= rows) return;

    float v = src[(size_t)row * K_DIM + lane];
    __hip_bfloat16 h = __float2bfloat16(v);
    float hf = __bfloat162float(h);
    __hip_bfloat16 l = __float2bfloat16(v - hf);

    const int band = row >> 7, r = row & 127;
    short* base = blob + (size_t)band * BAND_SHORTS;
    base[r * CPITCH + lane]        = *(short*)&h;
    base[9216 + r * CPITCH + lane] = *(short*)&l;

    float s = v * v;
    #pragma unroll
    for (int off = 32; off > 0; off >>= 1) s += __shfl_down(s, off, 64);
    if (lane == 0) {
        float* f = (float*)(base + 18432);
        f[r]       = s;
        f[128 + r] = __expf(-2.0f * log_sigmas[row]);
    }
}

// ---------------- main: 256(M) x 128(N) tile, byte-minimal ----------------
// Per-CU vmem-port byte model (R2..R10 + fill all land at ~8-12 B/cyc/CU of
// total load+store traffic): the limiter was never store shape, it was TOTAL
// bytes — previous kernels re-read c per row-band (R10: 637 MB of loads vs
// 268 MB stores). This tile loads (256 rows x + 128-col c-band) = 105 KB per
// 128 KB stored: total loads 218 MB, per-CU traffic 1.9 MB -> ~70 µs at the
// measured port rate.
// Structure: 256 thr = 4 waves; wave w owns M-rows [w*64,+64). x-frags for
// those 64 rows live in registers (16 bf16x8, loaded pre-barrier; 16
// consecutive 128 B rows per frag-pair -> L1-coalesced). c-band staged to
// LDS once (2368 coalesced f32x4), norms ride the same blob. K=64 is fully
// consumed per 16x16 tile (no k-loop) -> only 4 acc f32x4 live; after the
// single barrier the wave's vmem stream is STORES-ONLY (c/norms from LDS).
// MFMA orientation = R4-verified: A=centres, B=x; D col(lane&15)=M row,
// row(quad*4+reg)=N col -> f32x4 store per tile.
__global__ __launch_bounds__(256, 3) void rbf_main(
    const __hip_bfloat16* __restrict__ xhi, const __hip_bfloat16* __restrict__ xlo,
    const short* __restrict__ blob, const float* __restrict__ nx,
    float* __restrict__ out, int N)
{
    __shared__ __align__(16) short cs[BAND_SHORTS];   // 40960 B

    const int tid  = threadIdx.x;
    const int wave = tid >> 6;
    const int lane = tid & 63;
    const int quad = lane >> 4;
    const int l16  = lane & 15;

    const int band   = blockIdx.x;        // 0..N/128-1
    const int m_base = blockIdx.y << 8;   // 256 rows per block
    const int n_base = band << 7;

    // Stage the c-band blob: 2368 f32x4 slots, tid-linear (fully coalesced).
    {
        const f32x4* src = (const f32x4*)(blob + (size_t)band * BAND_SHORTS);
        f32x4* dst = (f32x4*)cs;
        #pragma unroll
        for (int i = 0; i < 10; ++i) {
            const int idx = tid + (i << 8);
            if (idx < 2368) dst[idx] = src[idx];
        }
    }

    // x-fragments for this wave's 64 rows (pre-barrier; the only global
    // loads besides staging). 4 M-groups x (hi k0,k1 + lo k0,k1).
    const int wbase = m_base + (wave << 6);
    bf16x8 xh0[4], xh1[4], xl0[4], xl1[4];
    float  nxm[4];
    #pragma unroll
    for (int mg = 0; mg < 4; ++mg) {
        const int xr = wbase + (mg << 4) + l16;
        const size_t ro = (size_t)xr * K_DIM + (quad << 3);
        xh0[mg] = *(const bf16x8*)(xhi + ro);
        xh1[mg] = *(const bf16x8*)(xhi + ro + 32);
        xl0[mg] = *(const bf16x8*)(xlo + ro);
        xl1[mg] = *(const bf16x8*)(xlo + ro + 32);
        nxm[mg] = nx[xr];
    }

    __syncthreads();

    const short* hbase = cs;
    const short* lbase = cs + 9216;
    const float* fbase = (const float*)(cs + 18432);

    for (int ng = 0; ng < 8; ++ng) {
        const int off = ((ng << 4) + l16) * CPITCH + (quad << 3);
        const bf16x8 ch0 = *(const bf16x8*)(hbase + off);
        const bf16x8 ch1 = *(const bf16x8*)(hbase + off + 32);
        const bf16x8 cl0 = *(const bf16x8*)(lbase + off);
        const bf16x8 cl1 = *(const bf16x8*)(lbase + off + 32);

        const int jc = (ng << 4) + (quad << 2);       // band-local col of 4 outputs
        const f32x4 nc4 = *(const f32x4*)&fbase[jc];
        const f32x4 iv4 = *(const f32x4*)&fbase[128 + jc];

        #pragma unroll
        for (int mg = 0; mg < 4; ++mg) {
            f32x4 acc = {0.f, 0.f, 0.f, 0.f};
            acc = __builtin_amdgcn_mfma_f32_16x16x32_bf16(ch0, xh0[mg], acc, 0, 0, 0);
            acc = __builtin_amdgcn_mfma_f32_16x16x32_bf16(ch1, xh1[mg], acc, 0, 0, 0);
            acc = __builtin_amdgcn_mfma_f32_16x16x32_bf16(ch0, xl0[mg], acc, 0, 0, 0);
            acc = __builtin_amdgcn_mfma_f32_16x16x32_bf16(ch1, xl1[mg], acc, 0, 0, 0);
            acc = __builtin_amdgcn_mfma_f32_16x16x32_bf16(cl0, xh0[mg], acc, 0, 0, 0);
            acc = __builtin_amdgcn_mfma_f32_16x16x32_bf16(cl1, xh1[mg], acc, 0, 0, 0);

            f32x4 res;
            #pragma unroll
            for (int r = 0; r < 4; ++r) {
                float sq = fmaxf(nxm[mg] + nc4[r] - 2.0f * acc[r], 0.f);
                res[r] = __expf(-sq * iv4[r]);
            }
            __builtin_nontemporal_store(
                res, (f32x4*)(out + (size_t)(wbase + (mg << 4) + l16) * N + n_base + jc));
        }
    }
}

// ---------------- fallback: fully fused (R2's passing kernel) ----------------
__device__ __forceinline__ void split8(const float* __restrict__ p,
                                       bf16x8& hi, bf16x8& lo, float& ss) {
    #pragma unroll
    for (int j = 0; j < 8; ++j) {
        float v = p[j];
        ss = fmaf(v, v, ss);
        __hip_bfloat16 h = __float2bfloat16(v);
        float hf = __bfloat162float(h);
        __hip_bfloat16 l = __float2bfloat16(v - hf);
        hi[j] = *reinterpret_cast<const short*>(&h);
        lo[j] = *reinterpret_cast<const short*>(&l);
    }
}

__global__ __launch_bounds__(256) void rbf_fused(
    const float* __restrict__ x, const float* __restrict__ c,
    const float* __restrict__ ls, float* __restrict__ out, int N)
{
    const int wave = threadIdx.x >> 6;
    const int lane = threadIdx.x & 63;
    const int quad = lane >> 4;
    const int l16  = lane & 15;

    const int m_base = (blockIdx.y << 6) + (wave << 4);
    const int n_base = blockIdx.x << 6;

    const int am = m_base + l16;
    const float* xp = x + (size_t)am * K_DIM;
    bf16x8 ahi0, alo0, ahi1, alo1;
    float ssx = 0.f;
    split8(xp + quad * 8,      ahi0, alo0, ssx);
    split8(xp + 32 + quad * 8, ahi1, alo1, ssx);
    ssx += __shfl_xor(ssx, 16, 64);
    ssx += __shfl_xor(ssx, 32, 64);
    float nxr[4];
    #pragma unroll
    for (int r = 0; r < 4; ++r) nxr[r] = __shfl(ssx, quad * 4 + r, 64);

    #pragma unroll
    for (int nt = 0; nt < 4; ++nt) {
        const int n = n_base + nt * 16 + l16;
        const float* cp = c + (size_t)n * K_DIM;
        bf16x8 bhi0, blo0, bhi1, blo1;
        float ssc = 0.f;
        split8(cp + quad * 8,      bhi0, blo0, ssc);
        split8(cp + 32 + quad * 8, bhi1, blo1, ssc);
        ssc += __shfl_xor(ssc, 16, 64);
        ssc += __shfl_xor(ssc, 32, 64);

        f32x4 acc = {0.f, 0.f, 0.f, 0.f};
        acc = __builtin_amdgcn_mfma_f32_16x16x32_bf16(ahi0, bhi0, acc, 0, 0, 0);
        acc = __builtin_amdgcn_mfma_f32_16x16x32_bf16(ahi1, bhi1, acc, 0, 0, 0);
        acc = __builtin_amdgcn_mfma_f32_16x16x32_bf16(ahi0, blo0, acc, 0, 0, 0);
        acc = __builtin_amdgcn_mfma_f32_16x16x32_bf16(ahi1, blo1, acc, 0, 0, 0);
        acc = __builtin_amdgcn_mfma_f32_16x16x32_bf16(alo0, bhi0, acc, 0, 0, 0);
        acc = __builtin_amdgcn_mfma_f32_16x16x32_bf16(alo1, bhi1, acc, 0, 0, 0);

        const float invv = __expf(-2.0f * ls[n]);
        #pragma unroll
        for (int r = 0; r < 4; ++r) {
            const int row = m_base + quad * 4 + r;
            float sq = fmaxf(nxr[r] + ssc - 2.0f * acc[r], 0.f);
            out[(size_t)row * N + n] = __expf(-sq * invv);
        }
    }
}

extern "C" void kernel_launch(void* const* d_in, const int* in_sizes, int n_in,
                              void* d_out, int out_size, void* d_ws, size_t ws_size,
                              hipStream_t stream) {
    const float* x  = (const float*)d_in[0];   // [M,64]
    const float* c  = (const float*)d_in[1];   // [N,64]
    const float* ls = (const float*)d_in[2];   // [N]
    float* out = (float*)d_out;                // [M,N]

    const int M = in_sizes[0] / K_DIM;   // 16384
    const int N = in_sizes[2];           // 4096

    size_t off = 0;
    auto place = [&](size_t bytes) { size_t p = off; off += (bytes + 255) & ~(size_t)255; return p; };
    size_t o_xhi  = place((size_t)M * K_DIM * 2);
    size_t o_xlo  = place((size_t)M * K_DIM * 2);
    size_t o_blob = place((size_t)(N / 128) * BAND_SHORTS * 2);
    size_t o_nx   = place((size_t)M * 4);

    if (ws_size >= off && (M % 256) == 0 && (N % 128) == 0) {
        char* ws = (char*)d_ws;
        __hip_bfloat16* xhi = (__hip_bfloat16*)(ws + o_xhi);
        __hip_bfloat16* xlo = (__hip_bfloat16*)(ws + o_xlo);
        short* blob = (short*)(ws + o_blob);
        float* nx   = (float*)(ws + o_nx);

        rbf_prep_x<<<dim3((M + 3) / 4), 256, 0, stream>>>(x, M, xhi, xlo, nx);
        rbf_prep_c<<<dim3((N + 3) / 4), 256, 0, stream>>>(c, N, blob, ls);
        rbf_main<<<dim3(N / 128, M / 256), 256, 0, stream>>>(xhi, xlo, blob, nx, out, N);
    } else {
        rbf_fused<<<dim3(N / 64, M / 64), 256, 0, stream>>>(x, c, ls, out, N);
    }
}